// Round 12
// baseline (30.716 us; speedup 1.0000x reference)
//
#include <hip/hip_runtime.h>
#include <hip/hip_bf16.h>

// y = relu(x @ W1 + b1) @ W2 + b2
// x:[B,64] f32, W1:[64,128], b1:[128], W2:[128,32], b2:[32], y:[B,32] f32
//
// R10/R11 body (LDS-free pi-permuted h, depth-1 pipeline, NT stores) +
// OCCUPANCY lever: weight fragments move from 96 persistent VGPRs to
// per-tile ds_read_b128 from LDS. LICM is defeated legitimately by keeping
// TWO identical LDS copies of each weight matrix and alternating copies by
// iteration parity (address is loop-variant -> values can't be hoisted,
// unlike R6; loads stay schedulable, unlike R9's volatile).
// VGPR cap 170 via launch_bounds(256,3): 3 waves/SIMD, 12 waves/CU,
// 768 blocks (3/CU, LDS 48KB x 3 = 144KB). Target: 2x outstanding x-bytes.
#define B_ROWS 262144
#define N_TILES (B_ROWS / 16)
#define W1COPY 8192
#define W2COPY 4096

typedef short short8 __attribute__((ext_vector_type(8)));
typedef float f32x4 __attribute__((ext_vector_type(4)));

__device__ inline short f2bf(float f) {
    __hip_bfloat16 h = __float2bfloat16(f);
    return __builtin_bit_cast(short, h);
}

__global__ __launch_bounds__(256, 3) void livenet_mlp(
    const float* __restrict__ x, const float* __restrict__ W1,
    const float* __restrict__ b1, const float* __restrict__ W2,
    const float* __restrict__ b2, float* __restrict__ y) {
    // Two identical swizzled copies of each transposed weight matrix:
    //  W1 elem [r][c] at short idx  c*64 + ((r>>3) ^ (c&7))*8      + (r&7)
    //  W2 elem [r][c] at short idx  c*128 + ((r>>3) ^ (2*(c&7)))*8 + (r&7)
    __shared__ __align__(16) short w1s[2 * W1COPY];  // 32 KB
    __shared__ __align__(16) short w2s[2 * W2COPY];  // 16 KB

    const int tid  = threadIdx.x;
    const int wid  = tid >> 6;
    const int lane = tid & 63;
    const int g    = lane >> 4;   // k-group 0..3
    const int q    = lane & 15;   // batch row within tile

    // ---- coalesced staging: global f32 -> LDS bf16^T, both copies ----
#pragma unroll
    for (int cp = 0; cp < 2; ++cp) {
#pragma unroll
        for (int p = 0; p < 8; ++p) {              // W1: 8192 elems
            const int idx = p * 1024 + tid * 4;
            f32x4 v = *(const f32x4*)(W1 + idx);
            const int r = idx >> 7, c = idx & 127;
#pragma unroll
            for (int e = 0; e < 4; ++e) {
                const int ce = c + e;
                w1s[cp * W1COPY + ce * 64 + (((r >> 3) ^ (ce & 7)) * 8) + (r & 7)] = f2bf(v[e]);
            }
        }
#pragma unroll
        for (int p = 0; p < 4; ++p) {              // W2: 4096 elems
            const int idx = p * 1024 + tid * 4;
            f32x4 v = *(const f32x4*)(W2 + idx);
            const int r = idx >> 5, c = idx & 31;
#pragma unroll
            for (int e = 0; e < 4; ++e) {
                const int ce = c + e;
                w2s[cp * W2COPY + ce * 128 + (((r >> 3) ^ (2 * (ce & 7))) * 8) + (r & 7)] = f2bf(v[e]);
            }
        }
    }
    __syncthreads();

    // ---- per-lane LDS frag offsets (short indices, precomputed) ----
    // w1 frag (ks,n): pc = pi(n,q); off = pc*64 + ((4ks+g)^(pc&7))*8
    int w1off[2][8];
#pragma unroll
    for (int ks = 0; ks < 2; ++ks)
#pragma unroll
        for (int n = 0; n < 8; ++n) {
            const int pc = 32 * (n & 3) + 8 * (q >> 2) + 4 * (n >> 2) + (q & 3);
            w1off[ks][n] = pc * 64 + ((4 * ks + g) ^ (pc & 7)) * 8;
        }
    int w2off[4][2];
#pragma unroll
    for (int ks = 0; ks < 4; ++ks)
#pragma unroll
        for (int n = 0; n < 2; ++n)
            w2off[ks][n] = (n * 16 + q) * 128 + ((4 * ks + g) ^ (2 * (q & 7))) * 8;

    // bias C-init (persistent, 40 VGPR): reg r = b1[pi(n,4g+r)]
    f32x4 binit1[8], binit2[2];
#pragma unroll
    for (int n = 0; n < 8; ++n)
        binit1[n] = *(const f32x4*)(b1 + 32 * (n & 3) + 8 * g + 4 * (n >> 2));
#pragma unroll
    for (int n = 0; n < 2; ++n)
        binit2[n] = *(const f32x4*)(b2 + n * 16 + 4 * g);

    const int gwave = blockIdx.x * 4 + wid;      // 0..3071
    const int S     = gridDim.x * 4;
    const float* xl = x + (size_t)q * 64 + g * 8;

    // ---- depth-1 pipeline with rotation ----
    f32x4 cur0, cur1, cur2, cur3, nxt0, nxt1, nxt2, nxt3;
    {
        const f32x4* p = (const f32x4*)(xl + (size_t)gwave * 1024);
        cur0 = p[0]; cur1 = p[1]; cur2 = p[8]; cur3 = p[9];
    }

    int parity = 0;
    for (int tile = gwave; tile < N_TILES; tile += S, parity ^= 1) {
        const int tn = tile + S;
        if (tn < N_TILES) {
            const f32x4* p = (const f32x4*)(xl + (size_t)tn * 1024);
            nxt0 = p[0]; nxt1 = p[1]; nxt2 = p[8]; nxt3 = p[9];
        }

        // copy bases alternate by iteration -> loads are not loop-invariant
        const short* w1b = w1s + parity * W1COPY;
        const short* w2b = w2s + parity * W2COPY;

        const int row0 = tile * 16;

        // ---- x B-fragments: elem j = bf16(x[row0+q][32ks+8g+j]) ----
        short8 a0, a1;
        {
            short8 v;
            v[0] = f2bf(cur0[0]); v[1] = f2bf(cur0[1]); v[2] = f2bf(cur0[2]); v[3] = f2bf(cur0[3]);
            v[4] = f2bf(cur1[0]); v[5] = f2bf(cur1[1]); v[6] = f2bf(cur1[2]); v[7] = f2bf(cur1[3]);
            a0 = v;
            v[0] = f2bf(cur2[0]); v[1] = f2bf(cur2[1]); v[2] = f2bf(cur2[2]); v[3] = f2bf(cur2[3]);
            v[4] = f2bf(cur3[0]); v[5] = f2bf(cur3[1]); v[6] = f2bf(cur3[2]); v[7] = f2bf(cur3[3]);
            a1 = v;
        }

        // ---- GEMM1 (swapped, pi-permuted); weight frags streamed from LDS ----
        f32x4 acc1[8];
#pragma unroll
        for (int n = 0; n < 8; ++n) {
            short8 wa = *(const short8*)&w1b[w1off[0][n]];
            short8 wb = *(const short8*)&w1b[w1off[1][n]];
            acc1[n] = __builtin_amdgcn_mfma_f32_16x16x32_bf16(wa, a0, binit1[n], 0, 0, 0);
            acc1[n] = __builtin_amdgcn_mfma_f32_16x16x32_bf16(wb, a1, acc1[n], 0, 0, 0);
        }

        // ---- in-register h repack: ha[ks][j] = relu(acc1[ks+4*(j>>2)][j&3])
        short8 ha[4];
#pragma unroll
        for (int ks = 0; ks < 4; ++ks) {
            short8 v;
            v[0] = f2bf(fmaxf(acc1[ks][0], 0.0f));
            v[1] = f2bf(fmaxf(acc1[ks][1], 0.0f));
            v[2] = f2bf(fmaxf(acc1[ks][2], 0.0f));
            v[3] = f2bf(fmaxf(acc1[ks][3], 0.0f));
            v[4] = f2bf(fmaxf(acc1[ks + 4][0], 0.0f));
            v[5] = f2bf(fmaxf(acc1[ks + 4][1], 0.0f));
            v[6] = f2bf(fmaxf(acc1[ks + 4][2], 0.0f));
            v[7] = f2bf(fmaxf(acc1[ks + 4][3], 0.0f));
            ha[ks] = v;
        }

        // ---- GEMM2 (swapped); w2 frags streamed from LDS ----
        f32x4 acc2[2];
#pragma unroll
        for (int n = 0; n < 2; ++n) {
            acc2[n] = binit2[n];
#pragma unroll
            for (int ks = 0; ks < 4; ++ks) {
                short8 w = *(const short8*)&w2b[w2off[ks][n]];
                acc2[n] = __builtin_amdgcn_mfma_f32_16x16x32_bf16(w, ha[ks], acc2[n], 0, 0, 0);
            }
        }

        // ---- store y: two dwordx4 per lane, coalesced, nontemporal ----
#pragma unroll
        for (int n = 0; n < 2; ++n)
            __builtin_nontemporal_store(
                acc2[n], (f32x4*)(y + (size_t)(row0 + q) * 32 + n * 16 + 4 * g));

        // ---- rotate pipeline ----
        cur0 = nxt0; cur1 = nxt1; cur2 = nxt2; cur3 = nxt3;
    }
}

extern "C" void kernel_launch(void* const* d_in, const int* in_sizes, int n_in,
                              void* d_out, int out_size, void* d_ws, size_t ws_size,
                              hipStream_t stream) {
    const float* x  = (const float*)d_in[0];
    const float* W1 = (const float*)d_in[1];
    const float* b1 = (const float*)d_in[2];
    const float* W2 = (const float*)d_in[3];
    const float* b2 = (const float*)d_in[4];
    float* y = (float*)d_out;

    // 768 blocks x 4 waves = 3072 waves; 3 blocks/CU (VGPR<=170, LDS 48KB):
    // 12 waves/CU -> 1.5x the concurrent load streams of the 24us plateau.
    const int blocks = 768;
    livenet_mlp<<<blocks, 256, 0, stream>>>(x, W1, b1, W2, b2, y);
}